// Round 19
// baseline (300.228 us; speedup 1.0000x reference)
//
#include <hip/hip_runtime.h>
#include <hip/hip_bf16.h>
#include <cstdint>
#include <cstddef>

#define TT 2048      // tokens (b*t)
#define DD 1024      // d
#define HH 2048      // h
#define NE 16        // experts
#define BROW 17      // B-tile row stride in u32 (64 rows x 17): 2-way-free banks both sides
#define XSLOT 12     // max m-groups per XCD (BM=256 -> ~16-20 groups total)

typedef __bf16 bf16x8 __attribute__((ext_vector_type(8)));
typedef float f32x4 __attribute__((ext_vector_type(4)));

// HW RNE via compiler casts -> v_cvt_pk_bf16_f32 pairing
__device__ __forceinline__ unsigned short f2bf(float f) {
  return __builtin_bit_cast(unsigned short, (__bf16)f);
}
__device__ __forceinline__ float bf2f(unsigned short s) {
  union { unsigned u; float f; } v; v.u = ((unsigned)s) << 16;
  return v.f;
}
__device__ __forceinline__ unsigned packbf(float lo, float hi) {
  unsigned short a = __builtin_bit_cast(unsigned short, (__bf16)lo);
  unsigned short b = __builtin_bit_cast(unsigned short, (__bf16)hi);
  return (unsigned)a | ((unsigned)b << 16);
}

__device__ __forceinline__ void gl_lds16(const void* g, void* l) {
  __builtin_amdgcn_global_load_lds(
      (const __attribute__((address_space(1))) unsigned int*)g,
      (__attribute__((address_space(3))) unsigned int*)l, 16, 0, 0);
}

union U4 { unsigned int u[4]; bf16x8 v; };

#define BARRIER_N(N)                                            \
  do {                                                          \
    asm volatile("s_waitcnt vmcnt(" #N ")" ::: "memory");       \
    asm volatile("s_waitcnt lgkmcnt(0)" ::: "memory");          \
    __builtin_amdgcn_sched_barrier(0);                          \
    __builtin_amdgcn_s_barrier();                               \
    __builtin_amdgcn_sched_barrier(0);                          \
  } while (0)

// ---------------- router + top-2 + bucketing + x cvt (fused) ----------------
__global__ __launch_bounds__(256) void k_router(
    const float* __restrict__ x, const float* __restrict__ rw,
    const float* __restrict__ rb, int* __restrict__ cnt,
    int* __restrict__ list_tok, int* __restrict__ rec,
    float* __restrict__ wrec, unsigned short* __restrict__ xbf) {
  const int t = blockIdx.x;
  __shared__ float xs[DD];
  __shared__ float part[256];
  __shared__ float sc[NE];
  const float* xr = x + (size_t)t * DD;
  for (int i = threadIdx.x; i < DD; i += 256) xs[i] = xr[i];
  __syncthreads();
  {
    int i = threadIdx.x * 4;
    ushort4 o = { f2bf(xs[i]), f2bf(xs[i + 1]), f2bf(xs[i + 2]), f2bf(xs[i + 3]) };
    *reinterpret_cast<ushort4*>(xbf + (size_t)t * DD + i) = o;
  }
  const int e = threadIdx.x >> 4, j = threadIdx.x & 15;
  const float* w = rw + (size_t)e * DD;
  float s = 0.f;
  for (int i = j; i < DD; i += 16) s += xs[i] * w[i];
  part[threadIdx.x] = s;
  __syncthreads();
  if (threadIdx.x < NE) {
    float v = rb[threadIdx.x];
    #pragma unroll
    for (int q = 0; q < 16; ++q) v += part[threadIdx.x * 16 + q];
    sc[threadIdx.x] = v;
  }
  __syncthreads();
  if (threadIdx.x == 0) {
    int e1 = 0; float v1 = sc[0];
    #pragma unroll
    for (int q = 1; q < NE; ++q) { if (sc[q] > v1) { v1 = sc[q]; e1 = q; } }
    int e2 = -1; float v2 = -3.4e38f;
    #pragma unroll
    for (int q = 0; q < NE; ++q) {
      if (q != e1 && sc[q] > v2) { v2 = sc[q]; e2 = q; }
    }
    float ex = expf(v2 - v1);
    float w1 = 1.f / (1.f + ex);
    float w2 = ex / (1.f + ex);
    int p1 = atomicAdd(&cnt[e1], 1);
    int p2 = atomicAdd(&cnt[e2], 1);
    list_tok[e1 * TT + p1] = t;
    list_tok[e2 * TT + p2] = t;
    rec[t * 4 + 0] = e1; rec[t * 4 + 1] = p1;
    rec[t * 4 + 2] = e2; rec[t * 4 + 3] = p2;
    wrec[t * 2 + 0] = w1; wrec[t * 2 + 1] = w2;
  }
}

// ---------------- work-table: expert-cohesive balanced XCD groups, BM=256 ----------------
__global__ void k_sched(const int* __restrict__ cnt, int* __restrict__ woff,
                        int* __restrict__ gtab, int* __restrict__ gcnt) {
  if (threadIdx.x == 0) {
    int o = 0;
    int nmb[NE], ord[NE];
    for (int e = 0; e < NE; ++e) {
      int ce = cnt[e];
      nmb[e] = (ce + 255) >> 8;        // 256-row m-groups (usually 1/expert)
      ord[e] = e;
      woff[e] = o; o += ce;
    }
    for (int i = 0; i < NE - 1; ++i) {
      int mx = i;
      for (int j = i + 1; j < NE; ++j)
        if (nmb[ord[j]] > nmb[ord[mx]]) mx = j;
      int t = ord[i]; ord[i] = ord[mx]; ord[mx] = t;
    }
    int gc[8];
    #pragma unroll
    for (int q = 0; q < 8; ++q) gc[q] = 0;
    for (int q = 0; q < 8 * XSLOT; ++q) gtab[q] = -1;
    for (int i = 0; i < NE; ++i) {
      int e = ord[i];
      int x = -1;
      for (int q = 0; q < 8; ++q)
        if (gc[q] + nmb[e] <= XSLOT && (x < 0 || gc[q] < gc[x])) x = q;
      if (x < 0) { x = 0; for (int q = 1; q < 8; ++q) if (gc[q] < gc[x]) x = q; }
      for (int mb = 0; mb < nmb[e] && gc[x] < XSLOT; ++mb) {
        gtab[x * XSLOT + gc[x]] = e * 256 + mb;
        gc[x]++;
      }
    }
    #pragma unroll
    for (int q = 0; q < 8; ++q) gcnt[q] = gc[q];
  }
}

__device__ __forceinline__ bool xcd_map(int L, const int* gtab, const int* gcnt,
                                        int NTSH, int& e, int& mt, int& nt) {
  int x = L & 7, r = L >> 3;
  int g = r >> NTSH;
  if (g >= gcnt[x]) return false;
  int v = gtab[x * XSLOT + g];
  if (v < 0) return false;
  e = v >> 8; mt = v & 255;
  nt = r & ((1 << NTSH) - 1);
  return true;
}

// ---------------- up GEMMs (mag,freq) + activation ----------------
// BM=256 (whole expert -> B read once), BN=64, BK=32. 4 waves 2x2: wave=128Mx32N.
// Counted-vmcnt barriers + 2-deep named B sets. lb(256,2): 128 AGPR acc fits.
__global__ __launch_bounds__(256, 2) void k_up(
    const unsigned short* __restrict__ xbf,
    const float* __restrict__ bmag,    // [e][DD][HH]
    const float* __restrict__ bfreq,   // [e][DD][HH]
    const float* __restrict__ bphase,
    const int* __restrict__ cnt, const int* __restrict__ list_tok,
    const int* __restrict__ gtab, const int* __restrict__ gcnt,
    const int* __restrict__ woff,
    unsigned short* __restrict__ hid) {
  int e, mt, nt;
  if (!xcd_map(blockIdx.x, gtab, gcnt, 5, e, mt, nt)) return;
  const int ce = cnt[e];
  const int off = woff[e];
  __shared__ unsigned short As[2][256][32];   // 32 KB
  __shared__ unsigned int BuM[2][64 * BROW];  // 8.5 KB
  __shared__ unsigned int BuF[2][64 * BROW];  // 8.5 KB
  __shared__ int toks[256];
  const int tid = threadIdx.x;
  {
    int r = mt * 256 + tid;
    toks[tid] = list_tok[e * TT + (r < ce ? r : ce - 1)];
  }
  __syncthreads();
  const int w = tid >> 6, l = tid & 63;
  // A staging: 4 chunks/thread, source-side XOR chunk swizzle
  size_t abase[4]; int aoff[4];
  #pragma unroll
  for (int p = 0; p < 4; ++p) {
    int row = p * 64 + w * 16 + (l >> 2);
    int g = (l & 3) ^ ((row >> 1) & 3);
    abase[p] = (size_t)toks[row] * DD + g * 8;
    aoff[p] = (p * 256 + w * 64 + l) * 8;
  }
  const int q2 = tid >> 4;
  const int b16 = tid & 15;
  const int n0 = nt * 64;
  const float* srcM = bmag  + (size_t)e * DD * HH + n0 + 4 * b16;
  const float* srcF = bfreq + (size_t)e * DD * HH + n0 + 4 * b16;
  int bwv[4];
  #pragma unroll
  for (int i = 0; i < 4; ++i) bwv[i] = (4 * b16 + i) * BROW + q2;

  const int wm = (w >> 1) * 128, wn = (w & 1) * 32;
  const int lr = l & 15, kg = l >> 4;
  const f32x4 zero = {0.f, 0.f, 0.f, 0.f};
  f32x4 accM[8][2], accF[8][2];
  #pragma unroll
  for (int a = 0; a < 8; ++a)
    #pragma unroll
    for (int b = 0; b < 2; ++b) { accM[a][b] = zero; accF[a][b] = zero; }

  float4 Am0, Am1, Af0, Af1;   // set A
  float4 Bm0, Bm1, Bf0, Bf1;   // set B

  auto glA = [&](int kt, int buf) {
    #pragma unroll
    for (int j = 0; j < 4; ++j)
      gl_lds16(xbf + abase[j] + kt * 32, &As[buf][0][0] + aoff[j]);
  };
  auto loadBA = [&](int kt) {
    const float* pM = srcM + (size_t)(kt * 32 + 2 * q2) * HH;
    const float* pF = srcF + (size_t)(kt * 32 + 2 * q2) * HH;
    Am0 = *reinterpret_cast<const float4*>(pM);
    Am1 = *reinterpret_cast<const float4*>(pM + HH);
    Af0 = *reinterpret_cast<const float4*>(pF);
    Af1 = *reinterpret_cast<const float4*>(pF + HH);
  };
  auto loadBB = [&](int kt) {
    const float* pM = srcM + (size_t)(kt * 32 + 2 * q2) * HH;
    const float* pF = srcF + (size_t)(kt * 32 + 2 * q2) * HH;
    Bm0 = *reinterpret_cast<const float4*>(pM);
    Bm1 = *reinterpret_cast<const float4*>(pM + HH);
    Bf0 = *reinterpret_cast<const float4*>(pF);
    Bf1 = *reinterpret_cast<const float4*>(pF + HH);
  };
  auto writeBA = [&](int buf) {
    const float* m0 = reinterpret_cast<const float*>(&Am0);
    const float* m1 = reinterpret_cast<const float*>(&Am1);
    const float* f0 = reinterpret_cast<const float*>(&Af0);
    const float* f1 = reinterpret_cast<const float*>(&Af1);
    #pragma unroll
    for (int i = 0; i < 4; ++i) {
      BuM[buf][bwv[i]] = packbf(m0[i], m1[i]);
      BuF[buf][bwv[i]] = packbf(f0[i], f1[i]);
    }
  };
  auto writeBB = [&](int buf) {
    const float* m0 = reinterpret_cast<const float*>(&Bm0);
    const float* m1 = reinterpret_cast<const float*>(&Bm1);
    const float* f0 = reinterpret_cast<const float*>(&Bf0);
    const float* f1 = reinterpret_cast<const float*>(&Bf1);
    #pragma unroll
    for (int i = 0; i < 4; ++i) {
      BuM[buf][bwv[i]] = packbf(m0[i], m1[i]);
      BuF[buf][bwv[i]] = packbf(f0[i], f1[i]);
    }
  };
  auto compute = [&](int buf) {
    U4 tm[2], tf[2];
    #pragma unroll
    for (int fn = 0; fn < 2; ++fn) {
      const int nb = (wn + fn * 16 + lr) * BROW + kg * 4;
      #pragma unroll
      for (int j2 = 0; j2 < 4; ++j2) {
        tm[fn].u[j2] = BuM[buf][nb + j2];
        tf[fn].u[j2] = BuF[buf][nb + j2];
      }
    }
    #pragma unroll
    for (int fm = 0; fm < 8; ++fm) {
      int row = wm + fm * 16 + lr;
      int c = kg ^ ((row >> 1) & 3);
      bf16x8 av = *reinterpret_cast<const bf16x8*>(&As[buf][row][c * 8]);
      #pragma unroll
      for (int fn = 0; fn < 2; ++fn) {
        accM[fm][fn] = __builtin_amdgcn_mfma_f32_16x16x32_bf16(av, tm[fn].v, accM[fm][fn], 0, 0, 0);
        accF[fm][fn] = __builtin_amdgcn_mfma_f32_16x16x32_bf16(av, tf[fn].v, accF[fm][fn], 0, 0, 0);
      }
    }
  };

  glA(0, 0);
  __builtin_amdgcn_sched_barrier(0);
  loadBA(0);
  loadBB(1);
  writeBA(0);
  BARRIER_N(4);
  for (int kt = 0; kt < 32; kt += 2) {
    glA(kt + 1, 1);
    __builtin_amdgcn_sched_barrier(0);
    loadBA(kt + 2 < 32 ? kt + 2 : 31);
    compute(0);
    writeBB(1);
    BARRIER_N(4);
    const bool more = kt + 2 < 32;
    if (more) {
      glA(kt + 2, 0);
      __builtin_amdgcn_sched_barrier(0);
      loadBB(kt + 3 < 32 ? kt + 3 : 31);
    }
    compute(1);
    if (more) {
      writeBA(0);
      BARRIER_N(4);
    }
  }
  #pragma unroll
  for (int fn = 0; fn < 2; ++fn) {
    const int ng = n0 + wn + fn * 16 + lr;
    const float ph = bphase[e * HH + ng] + 0.1f;
    #pragma unroll
    for (int fm = 0; fm < 8; ++fm) {
      #pragma unroll
      for (int jj = 0; jj < 4; ++jj) {
        int m = mt * 256 + wm + fm * 16 + kg * 4 + jj;
        if (m < ce) {
          float mv = accM[fm][fn][jj];
          float fv = accF[fm][fn][jj];
          float exn = __expf(-fabsf(fv));
          float sp = fmaxf(fv, 0.f) + __logf(1.f + exn);   // stable softplus
          float t2 = __expf(2.f * mv);
          float th = 1.f - 2.f / (t2 + 1.f);               // tanh
          float hv = th * __cosf(sp + ph);
          hid[(size_t)(off + m) * HH + ng] = f2bf(hv);
        }
      }
    }
  }
}

// ---------------- down GEMM ----------------
// BM=256, BN=64, BK=32; wave=128Mx32N, fm=8; 64 phases; acc 64 AGPR -> lb(256,3).
__global__ __launch_bounds__(256, 3) void k_down(
    const unsigned short* __restrict__ hid,
    const float* __restrict__ bdown,   // [e][HH][DD]
    const int* __restrict__ cnt,
    const int* __restrict__ gtab, const int* __restrict__ gcnt,
    const int* __restrict__ woff,
    unsigned short* __restrict__ op) {
  int e, mt, nt;
  if (!xcd_map(blockIdx.x, gtab, gcnt, 4, e, mt, nt)) return;
  const int ce = cnt[e];
  const int off = woff[e];
  __shared__ unsigned short As[2][256][32];   // 32 KB
  __shared__ unsigned int Bu[2][64 * BROW];   // 8.5 KB
  const int tid = threadIdx.x;
  const int w = tid >> 6, l = tid & 63;
  size_t abase[4]; int aoff[4];
  #pragma unroll
  for (int p = 0; p < 4; ++p) {
    int row = p * 64 + w * 16 + (l >> 2);
    int g = (l & 3) ^ ((row >> 1) & 3);
    int gr = mt * 256 + row; if (gr >= ce) gr = ce - 1;
    abase[p] = (size_t)(off + gr) * HH + g * 8;
    aoff[p] = (p * 256 + w * 64 + l) * 8;
  }
  const int q2 = tid >> 4;
  const int b16 = tid & 15;
  const int n0 = nt * 64;
  const float* srcD = bdown + (size_t)e * HH * DD + n0 + 4 * b16;
  int bwv[4];
  #pragma unroll
  for (int i = 0; i < 4; ++i) bwv[i] = (4 * b16 + i) * BROW + q2;

  const int wm = (w >> 1) * 128, wn = (w & 1) * 32;
  const int lr = l & 15, kg = l >> 4;
  const f32x4 zero = {0.f, 0.f, 0.f, 0.f};
  f32x4 acc[8][2];
  #pragma unroll
  for (int a = 0; a < 8; ++a)
    #pragma unroll
    for (int b = 0; b < 2; ++b) acc[a][b] = zero;

  float4 Ad0, Ad1;   // set A
  float4 Bd0, Bd1;   // set B

  auto glA = [&](int kt, int buf) {
    #pragma unroll
    for (int j = 0; j < 4; ++j)
      gl_lds16(hid + abase[j] + kt * 32, &As[buf][0][0] + aoff[j]);
  };
  auto loadBA = [&](int kt) {
    const float* pD = srcD + (size_t)(kt * 32 + 2 * q2) * DD;
    Ad0 = *reinterpret_cast<const float4*>(pD);
    Ad1 = *reinterpret_cast<const float4*>(pD + DD);
  };
  auto loadBB = [&](int kt) {
    const float* pD = srcD + (size_t)(kt * 32 + 2 * q2) * DD;
    Bd0 = *reinterpret_cast<const float4*>(pD);
    Bd1 = *reinterpret_cast<const float4*>(pD + DD);
  };
  auto writeBA = [&](int buf) {
    const float* d0 = reinterpret_cast<const float*>(&Ad0);
    const float* d1 = reinterpret_cast<const float*>(&Ad1);
    #pragma unroll
    for (int i = 0; i < 4; ++i) Bu[buf][bwv[i]] = packbf(d0[i], d1[i]);
  };
  auto writeBB = [&](int buf) {
    const float* d0 = reinterpret_cast<const float*>(&Bd0);
    const float* d1 = reinterpret_cast<const float*>(&Bd1);
    #pragma unroll
    for (int i = 0; i < 4; ++i) Bu[buf][bwv[i]] = packbf(d0[i], d1[i]);
  };
  auto compute = [&](int buf) {
    U4 t[2];
    #pragma unroll
    for (int fn = 0; fn < 2; ++fn) {
      const int nb = (wn + fn * 16 + lr) * BROW + kg * 4;
      #pragma unroll
      for (int j2 = 0; j2 < 4; ++j2) t[fn].u[j2] = Bu[buf][nb + j2];
    }
    #pragma unroll
    for (int fm = 0; fm < 8; ++fm) {
      int row = wm + fm * 16 + lr;
      int c = kg ^ ((row >> 1) & 3);
      bf16x8 av = *reinterpret_cast<const bf16x8*>(&As[buf][row][c * 8]);
      #pragma unroll
      for (int fn = 0; fn < 2; ++fn)
        acc[fm][fn] = __builtin_amdgcn_mfma_f32_16x16x32_bf16(av, t[fn].v, acc[fm][fn], 0, 0, 0);
    }
  };

  glA(0, 0);
  __builtin_amdgcn_sched_barrier(0);
  loadBA(0);
  loadBB(1);
  writeBA(0);
  BARRIER_N(2);
  for (int kt = 0; kt < 64; kt += 2) {
    glA(kt + 1, 1);
    __builtin_amdgcn_sched_barrier(0);
    loadBA(kt + 2 < 64 ? kt + 2 : 63);
    compute(0);
    writeBB(1);
    BARRIER_N(2);
    const bool more = kt + 2 < 64;
    if (more) {
      glA(kt + 2, 0);
      __builtin_amdgcn_sched_barrier(0);
      loadBB(kt + 3 < 64 ? kt + 3 : 63);
    }
    compute(1);
    if (more) {
      writeBA(0);
      BARRIER_N(2);
    }
  }
  #pragma unroll
  for (int fn = 0; fn < 2; ++fn) {
    const int ng = n0 + wn + fn * 16 + lr;
    #pragma unroll
    for (int fm = 0; fm < 8; ++fm) {
      #pragma unroll
      for (int jj = 0; jj < 4; ++jj) {
        int m = mt * 256 + wm + fm * 16 + kg * 4 + jj;
        if (m < ce)
          op[(size_t)(off + m) * DD + ng] = f2bf(acc[fm][fn][jj]);
      }
    }
  }
}

// ---------------- combine + RMSNorm ----------------
__global__ __launch_bounds__(256) void k_norm(
    const unsigned short* __restrict__ op, const int* __restrict__ woff,
    const int* __restrict__ rec, const float* __restrict__ wrec,
    const float* __restrict__ nw, float* __restrict__ out) {
  const int t = blockIdx.x;
  const int tid = threadIdx.x;
  __shared__ float red[4];
  const int e1 = rec[t * 4 + 0], p1 = rec[t * 4 + 1];
  const int e2 = rec[t * 4 + 2], p2 = rec[t * 4 + 3];
  const float w1 = wrec[t * 2 + 0], w2 = wrec[t * 2 + 1];
  const unsigned short* pa = op + (size_t)(woff[e1] + p1) * DD;
  const unsigned short* pb = op + (size_t)(woff[e2] + p2) * DD;
  float v[4]; float ss = 0.f;
  #pragma unroll
  for (int q = 0; q < 4; ++q) {
    int i = q * 256 + tid;
    v[q] = w1 * bf2f(pa[i]) + w2 * bf2f(pb[i]);
    ss += v[q] * v[q];
  }
  #pragma unroll
  for (int o = 32; o > 0; o >>= 1) ss += __shfl_xor(ss, o);
  if ((tid & 63) == 0) red[tid >> 6] = ss;
  __syncthreads();
  const float tot = red[0] + red[1] + red[2] + red[3];
  const float scl = rsqrtf(tot * (1.f / DD) + 1e-6f);
  #pragma unroll
  for (int q = 0; q < 4; ++q) {
    int i = q * 256 + tid;
    out[(size_t)t * DD + i] = v[q] * scl * nw[i];
  }
}

extern "C" void kernel_launch(void* const* d_in, const int* in_sizes, int n_in,
                              void* d_out, int out_size, void* d_ws, size_t ws_size,
                              hipStream_t stream) {
  const float* x      = (const float*)d_in[0];
  const float* rw     = (const float*)d_in[1];
  const float* rb     = (const float*)d_in[2];
  const float* bmag   = (const float*)d_in[3];
  const float* bfreq  = (const float*)d_in[4];
  const float* bphase = (const float*)d_in[5];
  const float* bdown  = (const float*)d_in[6];
  const float* nw     = (const float*)d_in[7];
  float* out = (float*)d_out;
  char* ws = (char*)d_ws;
  const size_t MB = 1024 * 1024;
  int*   cnt    = (int*)(ws + 0);          // 16 int
  int*   woff   = (int*)(ws + 2048);       // 16 int
  int*   gtab   = (int*)(ws + 2176);       // 8*XSLOT int
  int*   gcnt   = (int*)(ws + 3200);       // 8 int
  int*   list   = (int*)(ws + 4096);       // 16*2048 int
  int*   rec    = (int*)(ws + 139264);     // 2048*4 int
  float* wrec   = (float*)(ws + 172032);   // 2048*2 f32
  unsigned short* xbf = (unsigned short*)(ws + 1 * MB);    // 4 MB
  unsigned short* hid = (unsigned short*)(ws + 5 * MB);    // 16 MB
  unsigned short* op  = (unsigned short*)(ws + 21 * MB);   // 8 MB

  hipMemsetAsync(cnt, 0, 64, stream);
  k_router<<<TT, 256, 0, stream>>>(x, rw, rb, cnt, list, rec, wrec, xbf);
  k_sched<<<1, 64, 0, stream>>>(cnt, woff, gtab, gcnt);
  k_up<<<8 * XSLOT * 32, 256, 0, stream>>>(xbf, bmag, bfreq, bphase,
                                           cnt, list, gtab, gcnt, woff, hid);
  k_down<<<8 * XSLOT * 16, 256, 0, stream>>>(hid, bdown, cnt, gtab, gcnt, woff, op);
  k_norm<<<TT, 256, 0, stream>>>(op, woff, rec, wrec, nw, out);
}

// Round 20
// 260.961 us; speedup vs baseline: 1.1505x; 1.1505x over previous
//
#include <hip/hip_runtime.h>
#include <hip/hip_bf16.h>
#include <cstdint>
#include <cstddef>

#define TT 2048      // tokens (b*t)
#define DD 1024      // d
#define HH 2048      // h
#define NE 16        // experts
#define WM128 48     // max (expert, 128-row block) work items
#define BROW 17      // B-tile row stride in u32 (64 rows x 17): 2-way-free banks both sides

typedef __bf16 bf16x8 __attribute__((ext_vector_type(8)));
typedef float f32x4 __attribute__((ext_vector_type(4)));

// HW RNE via compiler casts -> v_cvt_pk_bf16_f32 pairing (R18-validated, bit-identical)
__device__ __forceinline__ unsigned short f2bf(float f) {
  return __builtin_bit_cast(unsigned short, (__bf16)f);
}
__device__ __forceinline__ float bf2f(unsigned short s) {
  union { unsigned u; float f; } v; v.u = ((unsigned)s) << 16;
  return v.f;
}
__device__ __forceinline__ unsigned packbf(float lo, float hi) {
  unsigned short a = __builtin_bit_cast(unsigned short, (__bf16)lo);
  unsigned short b = __builtin_bit_cast(unsigned short, (__bf16)hi);
  return (unsigned)a | ((unsigned)b << 16);
}

__device__ __forceinline__ void gl_lds16(const void* g, void* l) {
  __builtin_amdgcn_global_load_lds(
      (const __attribute__((address_space(1))) unsigned int*)g,
      (__attribute__((address_space(3))) unsigned int*)l, 16, 0, 0);
}

union U4 { unsigned int u[4]; bf16x8 v; };

// Counted-vmcnt barrier: certify own gl_lds landed (N newer B-loads may fly),
// LDS writes visible, then raw s_barrier (no vmcnt(0) drain).
#define BARRIER_N(N)                                            \
  do {                                                          \
    asm volatile("s_waitcnt vmcnt(" #N ")" ::: "memory");       \
    asm volatile("s_waitcnt lgkmcnt(0)" ::: "memory");          \
    __builtin_amdgcn_sched_barrier(0);                          \
    __builtin_amdgcn_s_barrier();                               \
    __builtin_amdgcn_sched_barrier(0);                          \
  } while (0)

// ---------------- router + top-2 + bucketing + x cvt (fused) ----------------
__global__ __launch_bounds__(256) void k_router(
    const float* __restrict__ x, const float* __restrict__ rw,
    const float* __restrict__ rb, int* __restrict__ cnt,
    int* __restrict__ list_tok, int* __restrict__ rec,
    float* __restrict__ wrec, unsigned short* __restrict__ xbf) {
  const int t = blockIdx.x;
  __shared__ float xs[DD];
  __shared__ float part[256];
  __shared__ float sc[NE];
  const float* xr = x + (size_t)t * DD;
  for (int i = threadIdx.x; i < DD; i += 256) xs[i] = xr[i];
  __syncthreads();
  {
    int i = threadIdx.x * 4;
    ushort4 o = { f2bf(xs[i]), f2bf(xs[i + 1]), f2bf(xs[i + 2]), f2bf(xs[i + 3]) };
    *reinterpret_cast<ushort4*>(xbf + (size_t)t * DD + i) = o;
  }
  const int e = threadIdx.x >> 4, j = threadIdx.x & 15;
  const float* w = rw + (size_t)e * DD;
  float s = 0.f;
  for (int i = j; i < DD; i += 16) s += xs[i] * w[i];
  part[threadIdx.x] = s;
  __syncthreads();
  if (threadIdx.x < NE) {
    float v = rb[threadIdx.x];
    #pragma unroll
    for (int q = 0; q < 16; ++q) v += part[threadIdx.x * 16 + q];
    sc[threadIdx.x] = v;
  }
  __syncthreads();
  if (threadIdx.x == 0) {
    int e1 = 0; float v1 = sc[0];
    #pragma unroll
    for (int q = 1; q < NE; ++q) { if (sc[q] > v1) { v1 = sc[q]; e1 = q; } }
    int e2 = -1; float v2 = -3.4e38f;
    #pragma unroll
    for (int q = 0; q < NE; ++q) {
      if (q != e1 && sc[q] > v2) { v2 = sc[q]; e2 = q; }
    }
    float ex = expf(v2 - v1);
    float w1 = 1.f / (1.f + ex);
    float w2 = ex / (1.f + ex);
    int p1 = atomicAdd(&cnt[e1], 1);
    int p2 = atomicAdd(&cnt[e2], 1);
    list_tok[e1 * TT + p1] = t;
    list_tok[e2 * TT + p2] = t;
    rec[t * 4 + 0] = e1; rec[t * 4 + 1] = p1;
    rec[t * 4 + 2] = e2; rec[t * 4 + 3] = p2;
    wrec[t * 2 + 0] = w1; wrec[t * 2 + 1] = w2;
  }
}

// ---------------- work-table builder + XCD-group metadata ----------------
__global__ void k_sched(const int* __restrict__ cnt, int* __restrict__ work128,
                        int* __restrict__ woff, int* __restrict__ nmb,
                        int* __restrict__ flag) {
  if (threadIdx.x == 0) {
    int o = 0, n1 = 0;
    for (int e = 0; e < NE; ++e) {
      int ce = cnt[e];
      int a = (ce + 127) >> 7;
      nmb[e] = a;
      for (int mb = 0; mb < a; ++mb) { work128[n1 * 2] = e; work128[n1 * 2 + 1] = mb; ++n1; }
      woff[e] = o; o += ce;
    }
    for (int q = n1; q < WM128; ++q) { work128[q * 2] = -1; work128[q * 2 + 1] = 0; }
    int f = 0;
    for (int xq = 0; xq < 8; ++xq)
      if (nmb[xq] + nmb[xq + 8] > 6) f = 1;   // per-XCD capacity overflow
    flag[0] = f;
  }
}

// Map linear block id -> (e, mt, nt) so that all nt-members of an (e, mt) group
// share one XCD (L % 8); expert e lives on XCD e % 8 (L2 weight reuse across
// the expert's m-groups). Fallback to linear work-table if capacity overflows.
__device__ __forceinline__ bool xcd_map(int L, const int* nmb, const int* flag,
                                        const int* work, int NTSH,
                                        int& e, int& mt, int& nt) {
  if (flag[0] == 0) {
    int x = L & 7, r = L >> 3;
    int m0 = nmb[x] << NTSH, m1 = nmb[x + 8] << NTSH;
    if (r < m0) { e = x; mt = r >> NTSH; nt = r & ((1 << NTSH) - 1); return true; }
    r -= m0;
    if (r < m1) { e = x + 8; mt = r >> NTSH; nt = r & ((1 << NTSH) - 1); return true; }
    return false;
  } else {
    int wq = L >> NTSH;
    e = work[wq * 2];
    if (e < 0) return false;
    mt = work[wq * 2 + 1];
    nt = L & ((1 << NTSH) - 1);
    return true;
  }
}

// ---------------- up GEMMs (mag,freq) + activation ----------------
// BK=32, counted vmcnt, 2-deep named B register sets, launch_bounds(256,3);
// e%8-pinned XCD-grouped block mapping (R15 = global best config).
__global__ __launch_bounds__(256, 3) void k_up(
    const unsigned short* __restrict__ xbf,
    const float* __restrict__ bmag,    // [e][DD][HH]
    const float* __restrict__ bfreq,   // [e][DD][HH]
    const float* __restrict__ bphase,
    const int* __restrict__ cnt, const int* __restrict__ list_tok,
    const int* __restrict__ work, const int* __restrict__ woff,
    const int* __restrict__ nmb, const int* __restrict__ flag,
    unsigned short* __restrict__ hid) {
  int e, mt, nt;
  if (!xcd_map(blockIdx.x, nmb, flag, work, 5, e, mt, nt)) return;
  const int ce = cnt[e];
  const int off = woff[e];
  __shared__ unsigned short As[2][128][32];   // 16 KB
  __shared__ unsigned int BuM[2][64 * BROW];  // 8.5 KB
  __shared__ unsigned int BuF[2][64 * BROW];  // 8.5 KB
  __shared__ int toks[128];
  const int tid = threadIdx.x;
  if (tid < 128) {
    int r = mt * 128 + tid;
    toks[tid] = list_tok[e * TT + (r < ce ? r : ce - 1)];
  }
  __syncthreads();
  const int w = tid >> 6, l = tid & 63;
  size_t abase[2]; int aoff[2];
  #pragma unroll
  for (int p = 0; p < 2; ++p) {
    int row = p * 64 + w * 16 + (l >> 2);
    int g = (l & 3) ^ ((row >> 1) & 3);
    abase[p] = (size_t)toks[row] * DD + g * 8;
    aoff[p] = (p * 256 + w * 64 + l) * 8;
  }
  const int q2 = tid >> 4;
  const int b16 = tid & 15;
  const int n0 = nt * 64;
  const float* srcM = bmag  + (size_t)e * DD * HH + n0 + 4 * b16;
  const float* srcF = bfreq + (size_t)e * DD * HH + n0 + 4 * b16;
  int bwv[4];
  #pragma unroll
  for (int i = 0; i < 4; ++i) bwv[i] = (4 * b16 + i) * BROW + q2;

  const int wm = (w >> 1) * 64, wn = (w & 1) * 32;
  const int lr = l & 15, kg = l >> 4;
  const f32x4 zero = {0.f, 0.f, 0.f, 0.f};
  f32x4 accM[4][2], accF[4][2];
  #pragma unroll
  for (int a = 0; a < 4; ++a)
    #pragma unroll
    for (int b = 0; b < 2; ++b) { accM[a][b] = zero; accF[a][b] = zero; }

  float4 Am0, Am1, Af0, Af1;   // set A
  float4 Bm0, Bm1, Bf0, Bf1;   // set B

  auto glA = [&](int kt, int buf) {
    #pragma unroll
    for (int j = 0; j < 2; ++j)
      gl_lds16(xbf + abase[j] + kt * 32, &As[buf][0][0] + aoff[j]);
  };
  auto loadBA = [&](int kt) {
    const float* pM = srcM + (size_t)(kt * 32 + 2 * q2) * HH;
    const float* pF = srcF + (size_t)(kt * 32 + 2 * q2) * HH;
    Am0 = *reinterpret_cast<const float4*>(pM);
    Am1 = *reinterpret_cast<const float4*>(pM + HH);
    Af0 = *reinterpret_cast<const float4*>(pF);
    Af1 = *reinterpret_cast<const float4*>(pF + HH);
  };
  auto loadBB = [&](int kt) {
    const float* pM = srcM + (size_t)(kt * 32 + 2 * q2) * HH;
    const float* pF = srcF + (size_t)(kt * 32 + 2 * q2) * HH;
    Bm0 = *reinterpret_cast<const float4*>(pM);
    Bm1 = *reinterpret_cast<const float4*>(pM + HH);
    Bf0 = *reinterpret_cast<const float4*>(pF);
    Bf1 = *reinterpret_cast<const float4*>(pF + HH);
  };
  auto writeBA = [&](int buf) {
    const float* m0 = reinterpret_cast<const float*>(&Am0);
    const float* m1 = reinterpret_cast<const float*>(&Am1);
    const float* f0 = reinterpret_cast<const float*>(&Af0);
    const float* f1 = reinterpret_cast<const float*>(&Af1);
    #pragma unroll
    for (int i = 0; i < 4; ++i) {
      BuM[buf][bwv[i]] = packbf(m0[i], m1[i]);
      BuF[buf][bwv[i]] = packbf(f0[i], f1[i]);
    }
  };
  auto writeBB = [&](int buf) {
    const float* m0 = reinterpret_cast<const float*>(&Bm0);
    const float* m1 = reinterpret_cast<const float*>(&Bm1);
    const float* f0 = reinterpret_cast<const float*>(&Bf0);
    const float* f1 = reinterpret_cast<const float*>(&Bf1);
    #pragma unroll
    for (int i = 0; i < 4; ++i) {
      BuM[buf][bwv[i]] = packbf(m0[i], m1[i]);
      BuF[buf][bwv[i]] = packbf(f0[i], f1[i]);
    }
  };
  auto compute = [&](int buf) {
    bf16x8 av[4];
    #pragma unroll
    for (int fm = 0; fm < 4; ++fm) {
      int row = wm + fm * 16 + lr;
      int c = kg ^ ((row >> 1) & 3);
      av[fm] = *reinterpret_cast<const bf16x8*>(&As[buf][row][c * 8]);
    }
    U4 tm[2], tf[2];
    #pragma unroll
    for (int fn = 0; fn < 2; ++fn) {
      const int nb = (wn + fn * 16 + lr) * BROW + kg * 4;
      #pragma unroll
      for (int j2 = 0; j2 < 4; ++j2) {
        tm[fn].u[j2] = BuM[buf][nb + j2];
        tf[fn].u[j2] = BuF[buf][nb + j2];
      }
    }
    #pragma unroll
    for (int fm = 0; fm < 4; ++fm)
      #pragma unroll
      for (int fn = 0; fn < 2; ++fn) {
        accM[fm][fn] = __builtin_amdgcn_mfma_f32_16x16x32_bf16(av[fm], tm[fn].v, accM[fm][fn], 0, 0, 0);
        accF[fm][fn] = __builtin_amdgcn_mfma_f32_16x16x32_bf16(av[fm], tf[fn].v, accF[fm][fn], 0, 0, 0);
      }
  };

  glA(0, 0);
  __builtin_amdgcn_sched_barrier(0);
  loadBA(0);
  loadBB(1);
  writeBA(0);
  BARRIER_N(4);
  for (int kt = 0; kt < 32; kt += 2) {
    glA(kt + 1, 1);
    __builtin_amdgcn_sched_barrier(0);
    loadBA(kt + 2 < 32 ? kt + 2 : 31);
    compute(0);
    writeBB(1);
    BARRIER_N(4);
    const bool more = kt + 2 < 32;
    if (more) {
      glA(kt + 2, 0);
      __builtin_amdgcn_sched_barrier(0);
      loadBB(kt + 3 < 32 ? kt + 3 : 31);
    }
    compute(1);
    if (more) {
      writeBA(0);
      BARRIER_N(4);
    }
  }
  #pragma unroll
  for (int fn = 0; fn < 2; ++fn) {
    const int ng = n0 + wn + fn * 16 + lr;
    const float ph = bphase[e * HH + ng] + 0.1f;
    #pragma unroll
    for (int fm = 0; fm < 4; ++fm) {
      #pragma unroll
      for (int jj = 0; jj < 4; ++jj) {
        int m = mt * 128 + wm + fm * 16 + kg * 4 + jj;
        if (m < ce) {
          float mv = accM[fm][fn][jj];
          float fv = accF[fm][fn][jj];
          float exn = __expf(-fabsf(fv));
          float sp = fmaxf(fv, 0.f) + __logf(1.f + exn);   // stable softplus
          float t2 = __expf(2.f * mv);
          float th = 1.f - 2.f / (t2 + 1.f);               // tanh
          float hv = th * __cosf(sp + ph);
          hid[(size_t)(off + m) * HH + ng] = f2bf(hv);
        }
      }
    }
  }
}

// ---------------- down GEMM ----------------
// BM=128, BN=64, BK=32 (25 KB LDS); counted vmcnt(2) + 2-deep B sets; 64 phases;
// e%8-pinned XCD mapping (16 nt-members per group).
__global__ __launch_bounds__(256, 4) void k_down(
    const unsigned short* __restrict__ hid,
    const float* __restrict__ bdown,   // [e][HH][DD]
    const int* __restrict__ cnt,
    const int* __restrict__ work, const int* __restrict__ woff,
    const int* __restrict__ nmb, const int* __restrict__ flag,
    unsigned short* __restrict__ op) {
  int e, mt, nt;
  if (!xcd_map(blockIdx.x, nmb, flag, work, 4, e, mt, nt)) return;
  const int ce = cnt[e];
  const int off = woff[e];
  __shared__ unsigned short As[2][128][32];   // 16 KB
  __shared__ unsigned int Bu[2][64 * BROW];   // 8.5 KB
  const int tid = threadIdx.x;
  const int w = tid >> 6, l = tid & 63;
  size_t abase[2]; int aoff[2];
  #pragma unroll
  for (int p = 0; p < 2; ++p) {
    int row = p * 64 + w * 16 + (l >> 2);
    int g = (l & 3) ^ ((row >> 1) & 3);
    int gr = mt * 128 + row; if (gr >= ce) gr = ce - 1;
    abase[p] = (size_t)(off + gr) * HH + g * 8;
    aoff[p] = (p * 256 + w * 64 + l) * 8;
  }
  const int q2 = tid >> 4;
  const int b16 = tid & 15;
  const int n0 = nt * 64;
  const float* srcD = bdown + (size_t)e * HH * DD + n0 + 4 * b16;
  int bwv[4];
  #pragma unroll
  for (int i = 0; i < 4; ++i) bwv[i] = (4 * b16 + i) * BROW + q2;

  const int wm = (w >> 1) * 64, wn = (w & 1) * 32;
  const int lr = l & 15, kg = l >> 4;
  const f32x4 zero = {0.f, 0.f, 0.f, 0.f};
  f32x4 acc[4][2];
  #pragma unroll
  for (int a = 0; a < 4; ++a)
    #pragma unroll
    for (int b = 0; b < 2; ++b) acc[a][b] = zero;

  float4 Ad0, Ad1;   // set A
  float4 Bd0, Bd1;   // set B

  auto glA = [&](int kt, int buf) {
    #pragma unroll
    for (int j = 0; j < 2; ++j)
      gl_lds16(hid + abase[j] + kt * 32, &As[buf][0][0] + aoff[j]);
  };
  auto loadBA = [&](int kt) {
    const float* pD = srcD + (size_t)(kt * 32 + 2 * q2) * DD;
    Ad0 = *reinterpret_cast<const float4*>(pD);
    Ad1 = *reinterpret_cast<const float4*>(pD + DD);
  };
  auto loadBB = [&](int kt) {
    const float* pD = srcD + (size_t)(kt * 32 + 2 * q2) * DD;
    Bd0 = *reinterpret_cast<const float4*>(pD);
    Bd1 = *reinterpret_cast<const float4*>(pD + DD);
  };
  auto writeBA = [&](int buf) {
    const float* d0 = reinterpret_cast<const float*>(&Ad0);
    const float* d1 = reinterpret_cast<const float*>(&Ad1);
    #pragma unroll
    for (int i = 0; i < 4; ++i) Bu[buf][bwv[i]] = packbf(d0[i], d1[i]);
  };
  auto writeBB = [&](int buf) {
    const float* d0 = reinterpret_cast<const float*>(&Bd0);
    const float* d1 = reinterpret_cast<const float*>(&Bd1);
    #pragma unroll
    for (int i = 0; i < 4; ++i) Bu[buf][bwv[i]] = packbf(d0[i], d1[i]);
  };
  auto compute = [&](int buf) {
    bf16x8 av[4];
    #pragma unroll
    for (int fm = 0; fm < 4; ++fm) {
      int row = wm + fm * 16 + lr;
      int c = kg ^ ((row >> 1) & 3);
      av[fm] = *reinterpret_cast<const bf16x8*>(&As[buf][row][c * 8]);
    }
    U4 t[2];
    #pragma unroll
    for (int fn = 0; fn < 2; ++fn) {
      const int nb = (wn + fn * 16 + lr) * BROW + kg * 4;
      #pragma unroll
      for (int j2 = 0; j2 < 4; ++j2) t[fn].u[j2] = Bu[buf][nb + j2];
    }
    #pragma unroll
    for (int fm = 0; fm < 4; ++fm)
      #pragma unroll
      for (int fn = 0; fn < 2; ++fn)
        acc[fm][fn] = __builtin_amdgcn_mfma_f32_16x16x32_bf16(av[fm], t[fn].v, acc[fm][fn], 0, 0, 0);
  };

  glA(0, 0);
  __builtin_amdgcn_sched_barrier(0);
  loadBA(0);
  loadBB(1);
  writeBA(0);
  BARRIER_N(2);
  for (int kt = 0; kt < 64; kt += 2) {
    glA(kt + 1, 1);
    __builtin_amdgcn_sched_barrier(0);
    loadBA(kt + 2 < 64 ? kt + 2 : 63);
    compute(0);
    writeBB(1);
    BARRIER_N(2);
    const bool more = kt + 2 < 64;
    if (more) {
      glA(kt + 2, 0);
      __builtin_amdgcn_sched_barrier(0);
      loadBB(kt + 3 < 64 ? kt + 3 : 63);
    }
    compute(1);
    if (more) {
      writeBA(0);
      BARRIER_N(2);
    }
  }
  #pragma unroll
  for (int fn = 0; fn < 2; ++fn) {
    const int ng = n0 + wn + fn * 16 + lr;
    #pragma unroll
    for (int fm = 0; fm < 4; ++fm) {
      #pragma unroll
      for (int jj = 0; jj < 4; ++jj) {
        int m = mt * 128 + wm + fm * 16 + kg * 4 + jj;
        if (m < ce)
          op[(size_t)(off + m) * DD + ng] = f2bf(acc[fm][fn][jj]);
      }
    }
  }
}

// ---------------- combine + RMSNorm ----------------
__global__ __launch_bounds__(256) void k_norm(
    const unsigned short* __restrict__ op, const int* __restrict__ woff,
    const int* __restrict__ rec, const float* __restrict__ wrec,
    const float* __restrict__ nw, float* __restrict__ out) {
  const int t = blockIdx.x;
  const int tid = threadIdx.x;
  __shared__ float red[4];
  const int e1 = rec[t * 4 + 0], p1 = rec[t * 4 + 1];
  const int e2 = rec[t * 4 + 2], p2 = rec[t * 4 + 3];
  const float w1 = wrec[t * 2 + 0], w2 = wrec[t * 2 + 1];
  const unsigned short* pa = op + (size_t)(woff[e1] + p1) * DD;
  const unsigned short* pb = op + (size_t)(woff[e2] + p2) * DD;
  float v[4]; float ss = 0.f;
  #pragma unroll
  for (int q = 0; q < 4; ++q) {
    int i = q * 256 + tid;
    v[q] = w1 * bf2f(pa[i]) + w2 * bf2f(pb[i]);
    ss += v[q] * v[q];
  }
  #pragma unroll
  for (int o = 32; o > 0; o >>= 1) ss += __shfl_xor(ss, o);
  if ((tid & 63) == 0) red[tid >> 6] = ss;
  __syncthreads();
  const float tot = red[0] + red[1] + red[2] + red[3];
  const float scl = rsqrtf(tot * (1.f / DD) + 1e-6f);
  #pragma unroll
  for (int q = 0; q < 4; ++q) {
    int i = q * 256 + tid;
    out[(size_t)t * DD + i] = v[q] * scl * nw[i];
  }
}

extern "C" void kernel_launch(void* const* d_in, const int* in_sizes, int n_in,
                              void* d_out, int out_size, void* d_ws, size_t ws_size,
                              hipStream_t stream) {
  const float* x      = (const float*)d_in[0];
  const float* rw     = (const float*)d_in[1];
  const float* rb     = (const float*)d_in[2];
  const float* bmag   = (const float*)d_in[3];
  const float* bfreq  = (const float*)d_in[4];
  const float* bphase = (const float*)d_in[5];
  const float* bdown  = (const float*)d_in[6];
  const float* nw     = (const float*)d_in[7];
  float* out = (float*)d_out;
  char* ws = (char*)d_ws;
  const size_t MB = 1024 * 1024;
  int*   cnt    = (int*)(ws + 0);          // 16 int
  int*   work1  = (int*)(ws + 128);        // WM128*2 int
  int*   woff   = (int*)(ws + 2048);       // 16 int
  int*   nmb    = (int*)(ws + 2176);       // 16 int
  int*   flag   = (int*)(ws + 2304);       // 1 int
  int*   list   = (int*)(ws + 4096);       // 16*2048 int
  int*   rec    = (int*)(ws + 139264);     // 2048*4 int
  float* wrec   = (float*)(ws + 172032);   // 2048*2 f32
  unsigned short* xbf = (unsigned short*)(ws + 1 * MB);    // 4 MB
  unsigned short* hid = (unsigned short*)(ws + 5 * MB);    // 16 MB
  unsigned short* op  = (unsigned short*)(ws + 21 * MB);   // 8 MB

  hipMemsetAsync(cnt, 0, 64, stream);
  k_router<<<TT, 256, 0, stream>>>(x, rw, rb, cnt, list, rec, wrec, xbf);
  k_sched<<<1, 64, 0, stream>>>(cnt, work1, woff, nmb, flag);
  k_up<<<WM128 * 32, 256, 0, stream>>>(xbf, bmag, bfreq, bphase,
                                       cnt, list, work1, woff, nmb, flag, hid);
  k_down<<<WM128 * 16, 256, 0, stream>>>(hid, bdown, cnt, work1, woff, nmb, flag, op);
  k_norm<<<TT, 256, 0, stream>>>(op, woff, rec, wrec, nw, out);
}